// Round 4
// baseline (334.760 us; speedup 1.0000x reference)
//
#include <hip/hip_runtime.h>
#include <hip/hip_bf16.h>

// DifferentiableXGB: logits = epilogue(x @ W1^T + b1)
//   split[b,n] = sum_d x[b,d]*W1[n,d] + b1[n]          (n = t*4+k, N=400)
//   S[b,t] = sum_k split[b,t,k]
//   logits[b,j] = sum_t fw[t]*S[b,t]*sum_k sigmoid(split[b,t,k])*fc_w[j,k] + fc_b[j]
//
// V12 = BARRIER-FREE direct-fragment kernel. No LDS in the k-loop.
// R10 post-mortem: V11 (reg-staged) == V9 (DMA) == ~116us -> staging
// mechanics irrelevant; the barrier-per-chunk + vmcnt(0) drain + 5 waves/CU
// structure IS the cost. Every chunk pays full global latency serially.
// V12 exploits the problem's shape: W1 bf16 = 0.8 MB -> L2-RESIDENT, so B
// fragments (16B/lane, exact MFMA layout) load straight from L2; A fragments
// load from fp32 x (2 x float4/lane/m-tile, rows' 128B fully consumed) and
// cvt in-register. Zero barriers in the loop: 10 free-running waves/CU,
// 2-deep named-register pipeline (literal offsets, ping-pong sets A/B).
//   - 640 thr = 10 waves = 2 mh (32 rows) x 5 nf (5 n-tiles); BM=64;
//     grid 512; 32 k-steps of 32.
//   - acc 40 + raw dbuf 72 + addr ~= 165 regs -> 3 waves/SIMD placement.
//   - A re-read 5x across nf: per-chunk window 8 KB -> L1/L2 absorbs.
//   - Only sync: one __syncthreads before the Pbuf output combine.

typedef __bf16 bf16x8 __attribute__((ext_vector_type(8)));
typedef float f32x4 __attribute__((ext_vector_type(4)));

#define B_ROWS 32768
#define D_DIM  1024
#define N_COLS 400
#define BM     64
#define NCHUNK 32          // 1024 / 32
#define THREADS 640        // 10 waves: mh = wave/5 (2), nf = wave%5 (5)
#define NTPW 5             // n-tiles (16 wide) per wave
#define MT   2             // m-tiles (16 tall) per wave (32 rows per mh)

__device__ __forceinline__ unsigned short f2bf(float f) {
    unsigned int u = __float_as_uint(f);
    u += 0x7FFFu + ((u >> 16) & 1u);   // RTNE
    return (unsigned short)(u >> 16);
}
__device__ __forceinline__ unsigned int pk2(float a, float b) {
    return (unsigned int)f2bf(a) | ((unsigned int)f2bf(b) << 16);
}
__device__ __forceinline__ uint4 cvt8u(float4 a, float4 b) {
    uint4 u;
    u.x = pk2(a.x, a.y); u.y = pk2(a.z, a.w);
    u.z = pk2(b.x, b.y); u.w = pk2(b.z, b.w);
    return u;
}
__device__ __forceinline__ bf16x8 cvt8(float4 a, float4 b) {
    return __builtin_bit_cast(bf16x8, cvt8u(a, b));
}

// tiny: W1 fp32 -> bf16 (1.6 MB read, 0.8 MB write; L2-hot afterwards)
__global__ void cvt_f32_bf16_kernel(const float* __restrict__ in,
                                    unsigned short* __restrict__ out) {
    size_t i = ((size_t)blockIdx.x * 256 + threadIdx.x) * 8;
    float4 v0 = *reinterpret_cast<const float4*>(in + i);
    float4 v1 = *reinterpret_cast<const float4*>(in + i + 4);
    *reinterpret_cast<uint4*>(out + i) = cvt8u(v0, v1);
}

// ---- macro machinery: every hot value is an individually named register ----
#define FOR_N_(OP, m) OP(m,0) OP(m,1) OP(m,2) OP(m,3) OP(m,4)
#define FOR_MN(OP) FOR_N_(OP,0) FOR_N_(OP,1)

#define DECL_ACC(m,n) f32x4 acc##m##n = {};
#define MFMA_MN(m,n) acc##m##n = __builtin_amdgcn_mfma_f32_16x16x32_bf16( \
        afr##m, bfr##n, acc##m##n, 0, 0, 0);

// MODE 0: A fp32 (fused cvt), B bf16 (ws). MODE 2: both fp32 direct.
template <int MODE>
__global__ __launch_bounds__(THREADS, 1) void xgb_v12(
    const float* __restrict__ x,
    const void*  __restrict__ b_any,
    const float* __restrict__ b1,
    const float* __restrict__ fw,
    const float* __restrict__ fcw,      // [2,4]
    const float* __restrict__ fcb,      // [2]
    float* __restrict__ out)            // [B,2]
{
    __shared__ float Pbuf[BM * NTPW * 2];                           // 2.5 KB

    const int tid  = threadIdx.x;
    const int wave = tid >> 6;
    const int lane = tid & 63;
    const int quad = lane >> 4;
    const int l15  = lane & 15;
    const int mh   = wave / 5;          // 0..1  (m half: 32 rows)
    const int nf   = wave % 5;          // 0..4  (n fifth: 5 tiles)
    const int row0 = blockIdx.x * BM;

    FOR_MN(DECL_ACC)                    // acc00..acc14, 10 x f32x4

    if (MODE == 0) {
        const unsigned short* w1b = (const unsigned short*)b_any;

        // A bases: m-tile m covers rows row0 + mh*32 + m*16 + l15,
        // k-span = quad*8 .. +7 (8 consecutive fp32 = 2 x float4).
        const float* pa0 = x + (size_t)(row0 + mh * 32 + l15) * D_DIM + quad * 8;
        const float* pa1 = pa0 + (size_t)16 * D_DIM;
        // B bases: n-tile n covers cols (nf*5+n)*16 + l15, same k-span,
        // bf16 -> one dwordx4 per tile per k-step. L2-resident.
        const unsigned short* pb0 = w1b + (size_t)((nf * NTPW + 0) * 16 + l15) * D_DIM + quad * 8;
        const unsigned short* pb1 = pb0 + (size_t)16 * D_DIM;
        const unsigned short* pb2 = pb1 + (size_t)16 * D_DIM;
        const unsigned short* pb3 = pb2 + (size_t)16 * D_DIM;
        const unsigned short* pb4 = pb3 + (size_t)16 * D_DIM;

        // ping-pong raw-load register sets X/Y (named, compile-time only)
        float4 arX00, arX01, arX10, arX11;
        float4 arY00, arY01, arY10, arY11;
        uint4  brX0, brX1, brX2, brX3, brX4;
        uint4  brY0, brY1, brY2, brY3, brY4;

#define GLOADS(S, c) do { \
        ar##S##00 = *reinterpret_cast<const float4*>(pa0 + (c) * 32);     \
        ar##S##01 = *reinterpret_cast<const float4*>(pa0 + (c) * 32 + 4); \
        ar##S##10 = *reinterpret_cast<const float4*>(pa1 + (c) * 32);     \
        ar##S##11 = *reinterpret_cast<const float4*>(pa1 + (c) * 32 + 4); \
        br##S##0  = *reinterpret_cast<const uint4*>(pb0 + (c) * 32);      \
        br##S##1  = *reinterpret_cast<const uint4*>(pb1 + (c) * 32);      \
        br##S##2  = *reinterpret_cast<const uint4*>(pb2 + (c) * 32);      \
        br##S##3  = *reinterpret_cast<const uint4*>(pb3 + (c) * 32);      \
        br##S##4  = *reinterpret_cast<const uint4*>(pb4 + (c) * 32);      \
        } while (0)

#define COMPUTE(S) do { \
        bf16x8 afr0 = cvt8(ar##S##00, ar##S##01); \
        bf16x8 afr1 = cvt8(ar##S##10, ar##S##11); \
        bf16x8 bfr0 = __builtin_bit_cast(bf16x8, br##S##0); \
        bf16x8 bfr1 = __builtin_bit_cast(bf16x8, br##S##1); \
        bf16x8 bfr2 = __builtin_bit_cast(bf16x8, br##S##2); \
        bf16x8 bfr3 = __builtin_bit_cast(bf16x8, br##S##3); \
        bf16x8 bfr4 = __builtin_bit_cast(bf16x8, br##S##4); \
        FOR_MN(MFMA_MN) \
        } while (0)

        // software pipeline, 2 deep: at PAIR(c) entry set X holds chunk c.
#define PAIR(c) GLOADS(Y, (c) + 1); COMPUTE(X); \
                GLOADS(X, (c) + 2); COMPUTE(Y);

        GLOADS(X, 0);
        PAIR(0)  PAIR(2)  PAIR(4)  PAIR(6)  PAIR(8)
        PAIR(10) PAIR(12) PAIR(14) PAIR(16) PAIR(18)
        PAIR(20) PAIR(22) PAIR(24) PAIR(26) PAIR(28)
        // tail: X holds chunk 30
        GLOADS(Y, 31); COMPUTE(X); COMPUTE(Y);
    } else {
        // fallback: both fp32 direct (no ws), simple loop
        const float* paf0 = x + (size_t)(row0 + mh * 32 + l15) * D_DIM + quad * 8;
        const float* paf1 = paf0 + (size_t)16 * D_DIM;
        const float* pbf0 = (const float*)b_any
                          + (size_t)((nf * NTPW + 0) * 16 + l15) * D_DIM + quad * 8;
        const float* pbf1 = pbf0 + (size_t)16 * D_DIM;
        const float* pbf2 = pbf1 + (size_t)16 * D_DIM;
        const float* pbf3 = pbf2 + (size_t)16 * D_DIM;
        const float* pbf4 = pbf3 + (size_t)16 * D_DIM;
        #pragma unroll 2
        for (int c = 0; c < NCHUNK; ++c) {
            const int off = c * 32;
            bf16x8 afr0, afr1;
            bf16x8 bfr0, bfr1, bfr2, bfr3, bfr4;
            afr0 = cvt8(*reinterpret_cast<const float4*>(paf0 + off),
                        *reinterpret_cast<const float4*>(paf0 + off + 4));
            afr1 = cvt8(*reinterpret_cast<const float4*>(paf1 + off),
                        *reinterpret_cast<const float4*>(paf1 + off + 4));
#define LBF2(n) bfr##n = cvt8(*reinterpret_cast<const float4*>(pbf##n + off), \
                              *reinterpret_cast<const float4*>(pbf##n + off + 4));
            LBF2(0) LBF2(1) LBF2(2) LBF2(3) LBF2(4)
            FOR_MN(MFMA_MN)
        }
    }

    // ---- epilogue ----
    // C/D layout: col = l15 (within tile), row = quad*4 + reg   [m89/m91]
    const float fcw0 = fcw[l15 & 3];        // fc_w[0][k], k = col&3
    const float fcw1 = fcw[4 + (l15 & 3)];  // fc_w[1][k]

#define PRE_N(n) \
    const float bias##n = b1[(nf * NTPW + (n)) * 16 + l15]; \
    const float tw##n   = fw[((nf * NTPW + (n)) * 16 + l15) >> 2];
    PRE_N(0) PRE_N(1) PRE_N(2) PRE_N(3) PRE_N(4)

    // per (m,r): q = sum over n of fw[t]*sigmoid(split)*S ; then 16-lane sum.
    // k-sum S: lanes ^1,^2 (l15 bits 0-1 are k within tree).
#define EPI_TERM(m,r,n) { \
        const float split_ = acc##m##n[r] + bias##n; \
        float s_ = split_; \
        s_ += __shfl_xor(s_, 1); \
        s_ += __shfl_xor(s_, 2); \
        const float leaf_ = 1.0f / (1.0f + __expf(-split_)); \
        const float val_ = tw##n * leaf_ * s_; \
        q0 += val_ * fcw0; q1 += val_ * fcw1; }

#define EPI_ONE(m,r) { \
        float q0 = 0.f, q1 = 0.f; \
        EPI_TERM(m,r,0) EPI_TERM(m,r,1) EPI_TERM(m,r,2) \
        EPI_TERM(m,r,3) EPI_TERM(m,r,4) \
        q0 += __shfl_xor(q0, 1); q0 += __shfl_xor(q0, 2); \
        q0 += __shfl_xor(q0, 4); q0 += __shfl_xor(q0, 8); \
        q1 += __shfl_xor(q1, 1); q1 += __shfl_xor(q1, 2); \
        q1 += __shfl_xor(q1, 4); q1 += __shfl_xor(q1, 8); \
        const int row_ = mh * 32 + (m) * 16 + quad * 4 + (r);   /* 0..63 */ \
        if (l15 == 0) Pbuf[(row_ * NTPW + nf) * 2 + 0] = q0; \
        if (l15 == 1) Pbuf[(row_ * NTPW + nf) * 2 + 1] = q1; }

#define EPI_M(m) EPI_ONE(m,0) EPI_ONE(m,1) EPI_ONE(m,2) EPI_ONE(m,3)
    EPI_M(0) EPI_M(1)

    __syncthreads();

    if (tid < 2 * BM) {
        const int r = tid >> 1, j = tid & 1;
        float s = fcb[j];
        #pragma unroll
        for (int w = 0; w < NTPW; ++w)
            s += Pbuf[(r * NTPW + w) * 2 + j];
        out[(row0 + r) * 2 + j] = s;
    }
}

extern "C" void kernel_launch(void* const* d_in, const int* in_sizes, int n_in,
                              void* d_out, int out_size, void* d_ws, size_t ws_size,
                              hipStream_t stream) {
    const float* x   = (const float*)d_in[0];
    const float* W1  = (const float*)d_in[1];
    const float* b1  = (const float*)d_in[2];
    const float* fw  = (const float*)d_in[3];
    const float* fcw = (const float*)d_in[4];
    const float* fcb = (const float*)d_in[5];
    float* out = (float*)d_out;

    const size_t w1_elems = (size_t)N_COLS * D_DIM;   // 409,600
    if (ws_size >= w1_elems * sizeof(unsigned short)) {
        unsigned short* w1b = (unsigned short*)d_ws;
        cvt_f32_bf16_kernel<<<(int)(w1_elems / 2048), 256, 0, stream>>>(W1, w1b);
        xgb_v12<0><<<B_ROWS / BM, THREADS, 0, stream>>>(
            x, (const void*)w1b, b1, fw, fcw, fcb, out);
    } else {
        xgb_v12<2><<<B_ROWS / BM, THREADS, 0, stream>>>(
            x, (const void*)W1, b1, fw, fcw, fcb, out);
    }
}

// Round 5
// 276.236 us; speedup vs baseline: 1.2119x; 1.2119x over previous
//
#include <hip/hip_runtime.h>
#include <hip/hip_bf16.h>

// DifferentiableXGB: logits = epilogue(x @ W1^T + b1)
//   split[b,n] = sum_d x[b,d]*W1[n,d] + b1[n]          (n = t*4+k, N=400)
//   S[b,t] = sum_k split[b,t,k]
//   logits[b,j] = sum_t fw[t]*S[b,t]*sum_k sigmoid(split[b,t,k])*fc_w[j,k] + fc_b[j]
//
// V13 = counted-vmcnt pipeline (T3/T4): raw s_barrier, NEVER vmcnt(0) in the
// main loop; loads for chunk c+1/c+2 stay in flight ACROSS the barrier.
// R11 post-mortem: V12 (no-LDS direct) regressed (194us, FETCH 109MB) ->
// latency-exposed. V8 (88us) limited by: A HBM stream (32KB/CU/chunk ~3300cy)
// covered only by one compute phase (~1000cy) because __syncthreads +
// WRITEA's data-dep wait drain everything each chunk.
// V13 discipline (each wave waits only ITS OWN staging; barrier rendezvous
// makes it global):
//   per chunk per thread: 4 B-DMAs (global_load_lds) issued FIRST, then
//   2 A-loads to regs (depth-2 ping-pong sets; chunk parity = set parity).
//   pre-barrier: s_waitcnt vmcnt(2)  -> retires own B(c), A(c+1) keeps flying
//               s_waitcnt lgkmcnt(0) -> own A ds_writes visible
//   WRITEA(c+1) consumes A regs a FULL iteration after issue (cover ~= chunk).
//   sched_barrier(0) pins DMA-before-A-load issue order (counts depend on it).
// Geometry: 512 thr = 8 waves (nf 0..7), BM=64, BK=32, NCHUNK=32, grid 512.
// N padded 400->512 in ws (pad cols: B=0, tw=0 -> exact zero contribution).
// LDS: A dbuf 8KB + B dbuf 64KB + P 4KB = 76KB. acc 16xf32x4 = 64 AGPR.
// launch_bounds(512,2): 2 waves/SIMD, cap 256 regs -> no spills.

typedef __bf16 bf16x8 __attribute__((ext_vector_type(8)));
typedef float f32x4 __attribute__((ext_vector_type(4)));

#define B_ROWS 32768
#define D_DIM  1024
#define N_COLS 400
#define NPAD   512
#define BM     64
#define BK     32
#define NCHUNK 32          // 1024 / 32
#define THREADS 512        // 8 waves: nf = wave (0..7)
#define NTPW 4             // n-tiles (16 wide) per wave (8*4 = 32 tiles = 512)
#define MT   4             // m-tiles (16 tall) per wave (all 64 rows)

__device__ __forceinline__ unsigned short f2bf(float f) {
    unsigned int u = __float_as_uint(f);
    u += 0x7FFFu + ((u >> 16) & 1u);   // RTNE
    return (unsigned short)(u >> 16);
}
__device__ __forceinline__ unsigned int pk2(float a, float b) {
    return (unsigned int)f2bf(a) | ((unsigned int)f2bf(b) << 16);
}
__device__ __forceinline__ uint4 cvt8u(float4 a, float4 b) {
    uint4 u;
    u.x = pk2(a.x, a.y); u.y = pk2(a.z, a.w);
    u.z = pk2(b.x, b.y); u.w = pk2(b.z, b.w);
    return u;
}
__device__ __forceinline__ bf16x8 cvt8(float4 a, float4 b) {
    return __builtin_bit_cast(bf16x8, cvt8u(a, b));
}

// W1 fp32 [400][1024] -> bf16 [512][1024] zero-padded (1 MB in ws)
__global__ void cvt_pad_bf16_kernel(const float* __restrict__ in,
                                    unsigned short* __restrict__ out) {
    size_t i = ((size_t)blockIdx.x * 256 + threadIdx.x) * 8;   // < 512*1024
    if (i < (size_t)N_COLS * D_DIM) {
        float4 v0 = *reinterpret_cast<const float4*>(in + i);
        float4 v1 = *reinterpret_cast<const float4*>(in + i + 4);
        *reinterpret_cast<uint4*>(out + i) = cvt8u(v0, v1);
    } else {
        uint4 z; z.x = z.y = z.z = z.w = 0u;
        *reinterpret_cast<uint4*>(out + i) = z;
    }
}

// async 16B/lane global->LDS; lds dest = wave-uniform base + lane*16 (HW)
__device__ __forceinline__ void gl_lds16(const unsigned short* g,
                                         unsigned short* l) {
    __builtin_amdgcn_global_load_lds(
        (const __attribute__((address_space(1))) unsigned int*)g,
        (__attribute__((address_space(3))) unsigned int*)l,
        16, 0, 0);
}

// ---- macro machinery: every hot value is an individually named register ----
#define FOR_N_(OP, m) OP(m,0) OP(m,1) OP(m,2) OP(m,3)
#define FOR_MN(OP) FOR_N_(OP,0) FOR_N_(OP,1) FOR_N_(OP,2) FOR_N_(OP,3)

#define DECL_ACC(m,n) f32x4 acc##m##n = {};
#define MFMA_MN(m,n) acc##m##n = __builtin_amdgcn_mfma_f32_16x16x32_bf16( \
        afr##m, bfr##n, acc##m##n, 0, 0, 0);

// MODE 0: A fp32 (fused cvt), B bf16 padded (ws). MODE 2: both fp32, plain.
template <int MODE>
__global__ __launch_bounds__(THREADS, 2) void xgb_v13(
    const float* __restrict__ x,
    const void*  __restrict__ b_any,
    const float* __restrict__ b1,
    const float* __restrict__ fw,
    const float* __restrict__ fcw,      // [2,4]
    const float* __restrict__ fcb,      // [2]
    float* __restrict__ out)            // [B,2]
{
    // rows of 32 shorts (64 B), sub = 8 shorts (16 B), 4 subs/row;
    // swizzle: phys_sub = (sub + (row>>1)) & 3   (V9-verified, 0 conflicts)
    __shared__ __align__(16) unsigned short Abuf[2][BM * BK];       // 8 KB
    __shared__ __align__(16) unsigned short Bbuf[2][NPAD * BK];     // 64 KB
    __shared__ float Pbuf[BM * 8 * 2];                              // 4 KB

    const int tid  = threadIdx.x;
    const int wave = tid >> 6;          // 0..7
    const int lane = tid & 63;
    const int quad = lane >> 4;
    const int l15  = lane & 15;
    const int nf   = wave;              // 4 n-tiles each
    const int row0 = blockIdx.x * BM;

    FOR_MN(DECL_ACC)                    // acc00..acc33, 16 x f32x4

    if (MODE == 0) {
        const unsigned short* w1b = (const unsigned short*)b_any;

        // ---- B staging: 32 DMA stages (16 rows = 1KB each), 4 per wave.
        // stage s: lane i -> row 16s+(i>>2), phys slot i&3; fetch logical
        // sub ((i&3) - (row>>1)) & 3 (pre-swizzled source).
#define BDECL(t) const unsigned short* bsrc##t; int bdst##t; \
        { const int s_ = wave + 8 * (t); const int rb_ = s_ * 16 + (lane >> 2); \
          const int cc_ = ((lane & 3) - (rb_ >> 1)) & 3; \
          bsrc##t = w1b + (size_t)rb_ * D_DIM + cc_ * 8; \
          bdst##t = s_ * 512; }                    // shorts
        BDECL(0) BDECL(1) BDECL(2) BDECL(3)

#define STAGEB(kc, Bb) do { \
        gl_lds16(bsrc0 + (kc), (Bb) + bdst0); \
        gl_lds16(bsrc1 + (kc), (Bb) + bdst1); \
        gl_lds16(bsrc2 + (kc), (Bb) + bdst2); \
        gl_lds16(bsrc3 + (kc), (Bb) + bdst3); } while (0)

        // ---- A staging: 64 rows x 4 subs = 256 slots; slot = tid & 255
        // (tid>=256 duplicates: identical loads/writes -> uniform vmcnt).
        const int slot = tid & 255;
        const int r0a = slot >> 2, c0a = slot & 3;
        const float* asrc0 = x + (size_t)(row0 + r0a) * D_DIM + c0a * 8;
        const int adst0 = r0a * 32 + ((c0a + (r0a >> 1)) & 3) * 8;   // swizzled
        // depth-2 ping-pong A sets; chunk parity == set parity
        float4 a0lo, a0hi, a1lo, a1hi;

#define LOADA0(kc) do { \
        a0lo = *reinterpret_cast<const float4*>(asrc0 + (kc));     \
        a0hi = *reinterpret_cast<const float4*>(asrc0 + (kc) + 4); } while (0)
#define LOADA1(kc) do { \
        a1lo = *reinterpret_cast<const float4*>(asrc0 + (kc));     \
        a1hi = *reinterpret_cast<const float4*>(asrc0 + (kc) + 4); } while (0)
#define WRITEA0(Ab) do { \
        *reinterpret_cast<uint4*>((Ab) + adst0) = cvt8u(a0lo, a0hi); } while (0)
#define WRITEA1(Ab) do { \
        *reinterpret_cast<uint4*>((Ab) + adst0) = cvt8u(a1lo, a1hi); } while (0)

#define LOAD_AFR(m) { const int row_ = (m) * 16 + l15; \
        const int p_ = (quad + (row_ >> 1)) & 3; \
        afr##m = *reinterpret_cast<const bf16x8*>(Ab_ + row_ * 32 + p_ * 8); }
#define LOAD_BFR(n) { const int row_ = (nf * NTPW + (n)) * 16 + l15; \
        const int p_ = (quad + (row_ >> 1)) & 3; \
        bfr##n = *reinterpret_cast<const bf16x8*>(Bb_ + row_ * 32 + p_ * 8); }

        // ---- prologue: chunk 0 staged into buf0; chunk 1 A-loads flying.
        STAGEB(0, Bbuf[0]);
        __builtin_amdgcn_sched_barrier(0);
        LOADA0(0);
        WRITEA0(Abuf[0]);               // auto-drains (one-time)
        __builtin_amdgcn_sched_barrier(0);
        LOADA1(BK);                     // chunk 1 -> set 1, stays in flight

        #pragma unroll 1
        for (int c = 0; c < NCHUNK; ++c) {
            const int cur = c & 1;
            const unsigned short* Ab_ = Abuf[cur];
            const unsigned short* Bb_ = Bbuf[cur];
            // each wave retires its OWN chunk-c staging; barrier rendezvous
            // makes it global. A(c+1) loads (2 newest vmem ops) keep flying.
            if (c == NCHUNK - 1) {
                asm volatile("s_waitcnt vmcnt(0)" ::: "memory");
            } else {
                asm volatile("s_waitcnt vmcnt(2)" ::: "memory");
            }
            asm volatile("s_waitcnt lgkmcnt(0)" ::: "memory");
            __builtin_amdgcn_s_barrier();
            __builtin_amdgcn_sched_barrier(0);
            if (c + 1 < NCHUNK) {
                STAGEB((c + 1) * BK, Bbuf[1 - cur]);   // 4 DMAs FIRST
                __builtin_amdgcn_sched_barrier(0);
                if (c + 2 < NCHUNK) {                  // then 2 A-loads
                    if (cur == 0) LOADA0((c + 2) * BK);
                    else          LOADA1((c + 2) * BK);
                }
                __builtin_amdgcn_sched_barrier(0);
            }
            {
                bf16x8 afr0, afr1, afr2, afr3;
                bf16x8 bfr0, bfr1, bfr2, bfr3;
                LOAD_AFR(0) LOAD_AFR(1) LOAD_AFR(2) LOAD_AFR(3)
                LOAD_BFR(0) LOAD_BFR(1) LOAD_BFR(2) LOAD_BFR(3)
                FOR_MN(MFMA_MN)
            }
            if (c + 1 < NCHUNK) {       // chunk c+1 lives in set 1-cur
                if (cur == 0) WRITEA1(Abuf[1]);
                else          WRITEA0(Abuf[0]);
            }
        }
    } else {
        // fallback: both fp32 direct (no ws), clamped pad rows, plain loop
        const float* af = x + (size_t)(row0 + l15) * D_DIM + quad * 8;
#define PBF(n) const float* pbf##n; { \
        int r_ = (nf * NTPW + (n)) * 16 + l15; if (r_ > N_COLS - 1) r_ = 0; \
        pbf##n = (const float*)b_any + (size_t)r_ * D_DIM + quad * 8; }
        PBF(0) PBF(1) PBF(2) PBF(3)
        for (int step = 0; step < NCHUNK; ++step) {
            const int off = step * BK;
            bf16x8 afr0, afr1, afr2, afr3;
            bf16x8 bfr0, bfr1, bfr2, bfr3;
#define LAF2(m) afr##m = cvt8( \
            *reinterpret_cast<const float4*>(af + (size_t)(m) * 16 * D_DIM + off), \
            *reinterpret_cast<const float4*>(af + (size_t)(m) * 16 * D_DIM + off + 4));
#define LBF2(n) bfr##n = cvt8( \
            *reinterpret_cast<const float4*>(pbf##n + off), \
            *reinterpret_cast<const float4*>(pbf##n + off + 4));
            LAF2(0) LAF2(1) LAF2(2) LAF2(3)
            LBF2(0) LBF2(1) LBF2(2) LBF2(3)
            FOR_MN(MFMA_MN)
        }
    }

    // ---- epilogue ----
    // C/D layout: col = l15 (within tile), row = quad*4 + reg   [m89/m91]
    const float fcw0 = fcw[l15 & 3];        // fc_w[0][k], k = col&3
    const float fcw1 = fcw[4 + (l15 & 3)];  // fc_w[1][k]

    // pad cols (>=400): bias=0, tw=0 -> exact zero contribution
#define PRE_N(n) \
    const int  col##n  = (nf * NTPW + (n)) * 16 + l15; \
    const bool ok##n   = (col##n < N_COLS); \
    const float bias##n = ok##n ? b1[ok##n ? col##n : 0] : 0.0f; \
    const float tw##n   = ok##n ? fw[ok##n ? (col##n >> 2) : 0] : 0.0f;
    PRE_N(0) PRE_N(1) PRE_N(2) PRE_N(3)

    // per (m,r): q = sum over n of fw[t]*sigmoid(split)*S ; then 16-lane sum.
    // k-sum S: lanes ^1,^2 (l15 bits 0-1 are k within tree).
#define EPI_TERM(m,r,n) { \
        const float split_ = acc##m##n[r] + bias##n; \
        float s_ = split_; \
        s_ += __shfl_xor(s_, 1); \
        s_ += __shfl_xor(s_, 2); \
        const float leaf_ = 1.0f / (1.0f + __expf(-split_)); \
        const float val_ = tw##n * leaf_ * s_; \
        q0 += val_ * fcw0; q1 += val_ * fcw1; }

#define EPI_ONE(m,r) { \
        float q0 = 0.f, q1 = 0.f; \
        EPI_TERM(m,r,0) EPI_TERM(m,r,1) EPI_TERM(m,r,2) EPI_TERM(m,r,3) \
        q0 += __shfl_xor(q0, 1); q0 += __shfl_xor(q0, 2); \
        q0 += __shfl_xor(q0, 4); q0 += __shfl_xor(q0, 8); \
        q1 += __shfl_xor(q1, 1); q1 += __shfl_xor(q1, 2); \
        q1 += __shfl_xor(q1, 4); q1 += __shfl_xor(q1, 8); \
        const int row_ = (m) * 16 + quad * 4 + (r);           /* 0..63 */ \
        if (l15 == 0) Pbuf[(row_ * 8 + nf) * 2 + 0] = q0; \
        if (l15 == 1) Pbuf[(row_ * 8 + nf) * 2 + 1] = q1; }

#define EPI_M(m) EPI_ONE(m,0) EPI_ONE(m,1) EPI_ONE(m,2) EPI_ONE(m,3)
    EPI_M(0) EPI_M(1) EPI_M(2) EPI_M(3)

    __syncthreads();

    if (tid < 2 * BM) {
        const int r = tid >> 1, j = tid & 1;
        float s = fcb[j];
        #pragma unroll
        for (int w = 0; w < 8; ++w)
            s += Pbuf[(r * 8 + w) * 2 + j];
        out[(row0 + r) * 2 + j] = s;
    }
}

extern "C" void kernel_launch(void* const* d_in, const int* in_sizes, int n_in,
                              void* d_out, int out_size, void* d_ws, size_t ws_size,
                              hipStream_t stream) {
    const float* x   = (const float*)d_in[0];
    const float* W1  = (const float*)d_in[1];
    const float* b1  = (const float*)d_in[2];
    const float* fw  = (const float*)d_in[3];
    const float* fcw = (const float*)d_in[4];
    const float* fcb = (const float*)d_in[5];
    float* out = (float*)d_out;

    const size_t pad_elems = (size_t)NPAD * D_DIM;    // 524,288
    if (ws_size >= pad_elems * sizeof(unsigned short)) {
        unsigned short* w1b = (unsigned short*)d_ws;
        cvt_pad_bf16_kernel<<<(int)(pad_elems / 2048), 256, 0, stream>>>(W1, w1b);
        xgb_v13<0><<<B_ROWS / BM, THREADS, 0, stream>>>(
            x, (const void*)w1b, b1, fw, fcw, fcb, out);
    } else {
        xgb_v13<2><<<B_ROWS / BM, THREADS, 0, stream>>>(
            x, (const void*)W1, b1, fw, fcw, fcb, out);
    }
}

// Round 6
// 229.425 us; speedup vs baseline: 1.4591x; 1.2040x over previous
//
#include <hip/hip_runtime.h>
#include <hip/hip_bf16.h>

// DifferentiableXGB: logits = epilogue(x @ W1^T + b1)
//   split[b,n] = sum_d x[b,d]*W1[n,d] + b1[n]          (n = t*4+k, N=400)
//   S[b,t] = sum_k split[b,t,k]
//   logits[b,j] = sum_t fw[t]*S[b,t]*sum_k sigmoid(split[b,t,k])*fc_w[j,k] + fc_b[j]
//
// V14 = V8 geometry-class (BM=128, BK=64, 16 chunks) rebuilt for a DEPTH-2
// A-pipeline under counted-vmcnt raw barriers.
// R12 model (fits V8..V13): per chunk the CU must pull 32KB of A from HBM
// (~3300cy at ~10B/cy/CU share) = the 21us floor; V8 exposes ~2kcy extra
// per chunk because A(c+1) is issued post-barrier(c) and consumed right
// after compute(c) (~1 chunk cover). Co-residency is register-impossible
// (acc 80 AGPR x waves x 512/SIMD). Fix: 2-chunk A lead. That needs a 2nd
// A reg set, which 640thr/164reg can't afford -> 512 thr = 8 waves =
// 2 waves/SIMD = 256-reg budget.
//   - 8 waves = 2 mh x 4 nf; NT=7; N padded 400->448 (12% B waste; pad
//     cols get B=0 and tw=bias=0 in epilogue -> exact zero contribution).
//   - A: 1024 subs = 512 thr x 2 slots UNIFORM (slot1 = +64 rows, same
//     swizzle phase); fp32 ping-pong sets X/Y (32 VGPR), 2 chunks ahead.
//   - B: 56 DMA stages of 8 rows = 7/wave UNIFORM (global_load_lds x4).
//   - per-wave invariant at loop top: outstanding = 7 DMA(c) + 4 A(c+1);
//     s_waitcnt vmcnt(4) retires own DMAs, A keeps flying ACROSS s_barrier;
//     lgkmcnt(0) covers own ds_writes + ds_reads (WAR). sched_barrier(0)
//     fences per rule #18. Order: STAGEB(c+1) -> WRITEA(c+1) -> LOADA(c+2)
//     -> compute(c).
//   - XOR-rotate swizzle phys_sub=(sub+row)&7 (V8-verified, 0 conflicts).
//   - launch_bounds(512,2): ~232 of 256 regs (112 AGPR acc), no spills.

typedef __bf16 bf16x8 __attribute__((ext_vector_type(8)));
typedef float f32x4 __attribute__((ext_vector_type(4)));

#define B_ROWS 32768
#define D_DIM  1024
#define N_COLS 400
#define NPAD   448
#define BM     128
#define BK     64
#define NCHUNK 16          // 1024 / 64
#define THREADS 512        // 8 waves: mh = wave>>2, nf = wave&3
#define NTPW 7             // n-tiles (16 wide) per wave (4*7 = 28 = 448)
#define MT   4             // m-tiles (16 tall) per wave (64 rows per mh)

__device__ __forceinline__ unsigned short f2bf(float f) {
    unsigned int u = __float_as_uint(f);
    u += 0x7FFFu + ((u >> 16) & 1u);   // RTNE
    return (unsigned short)(u >> 16);
}
__device__ __forceinline__ unsigned int pk2(float a, float b) {
    return (unsigned int)f2bf(a) | ((unsigned int)f2bf(b) << 16);
}
__device__ __forceinline__ uint4 cvt8u(float4 a, float4 b) {
    uint4 u;
    u.x = pk2(a.x, a.y); u.y = pk2(a.z, a.w);
    u.z = pk2(b.x, b.y); u.w = pk2(b.z, b.w);
    return u;
}
__device__ __forceinline__ bf16x8 cvt8(float4 a, float4 b) {
    return __builtin_bit_cast(bf16x8, cvt8u(a, b));
}

// W1 fp32 [400][1024] -> bf16 [448][1024] zero-padded (0.9 MB in ws)
__global__ void cvt_pad_bf16_kernel(const float* __restrict__ in,
                                    unsigned short* __restrict__ out) {
    size_t i = ((size_t)blockIdx.x * 256 + threadIdx.x) * 8;   // < 448*1024
    if (i < (size_t)N_COLS * D_DIM) {
        float4 v0 = *reinterpret_cast<const float4*>(in + i);
        float4 v1 = *reinterpret_cast<const float4*>(in + i + 4);
        *reinterpret_cast<uint4*>(out + i) = cvt8u(v0, v1);
    } else {
        uint4 z; z.x = z.y = z.z = z.w = 0u;
        *reinterpret_cast<uint4*>(out + i) = z;
    }
}

// async 16B/lane global->LDS; lds dest = wave-uniform base + lane*16 (HW)
__device__ __forceinline__ void gl_lds16(const unsigned short* g,
                                         unsigned short* l) {
    __builtin_amdgcn_global_load_lds(
        (const __attribute__((address_space(1))) unsigned int*)g,
        (__attribute__((address_space(3))) unsigned int*)l,
        16, 0, 0);
}

// ---- macro machinery: every hot value is an individually named register ----
#define FOR_N_(OP, m) OP(m,0) OP(m,1) OP(m,2) OP(m,3) OP(m,4) OP(m,5) OP(m,6)
#define FOR_MN(OP) FOR_N_(OP,0) FOR_N_(OP,1) FOR_N_(OP,2) FOR_N_(OP,3)

#define DECL_ACC(m,n) f32x4 acc##m##n = {};
#define MFMA_MN(m,n) acc##m##n = __builtin_amdgcn_mfma_f32_16x16x32_bf16( \
        afr##m, bfr##n, acc##m##n, 0, 0, 0);

// MODE 0: A fp32 (fused cvt), B bf16 padded (ws). MODE 2: both fp32, plain.
template <int MODE>
__global__ __launch_bounds__(THREADS, 2) void xgb_v14(
    const float* __restrict__ x,
    const void*  __restrict__ b_any,
    const float* __restrict__ b1,
    const float* __restrict__ fw,
    const float* __restrict__ fcw,      // [2,4]
    const float* __restrict__ fcb,      // [2]
    float* __restrict__ out)            // [B,2]
{
    // rows of 64 shorts (128 B), sub = 8 shorts (16 B), 8 subs/row;
    // swizzle: phys_sub = (sub + row) & 7   (V8-verified, 0 conflicts)
    __shared__ __align__(16) unsigned short Abuf[2][BM * BK];       // 32 KB
    __shared__ __align__(16) unsigned short Bbuf[2][NPAD * BK];     // 112 KB
    __shared__ float Pbuf[BM * 4 * 2];                              // 4 KB

    const int tid  = threadIdx.x;
    const int wave = tid >> 6;          // 0..7
    const int lane = tid & 63;
    const int quad = lane >> 4;
    const int l15  = lane & 15;
    const int mh   = wave >> 2;         // 0..1  (m half: 64 rows)
    const int nf   = wave & 3;          // 0..3  (n quarter: 7 tiles)
    const int row0 = blockIdx.x * BM;

    FOR_MN(DECL_ACC)                    // acc00..acc36, 28 x f32x4

    if (MODE == 0) {
        const unsigned short* w1b = (const unsigned short*)b_any;

        // ---- B staging: 56 DMA stages (8 rows = 1 KB each), 7 per wave.
        // stage s covers rows 8s..8s+7. lane i -> row 8s+(i>>3), phys slot
        // i&7; fetch the logical sub for that slot: ((i&7) - row) & 7.
#define BDECL(t) const unsigned short* bsrc##t; int bdst##t; \
        { const int s_ = wave + 8 * (t); const int rr_ = lane >> 3; \
          const int cc_ = ((lane & 7) - rr_) & 7; \
          bsrc##t = w1b + (size_t)(s_ * 8 + rr_) * D_DIM + cc_ * 8; \
          bdst##t = s_ * 512; }                    // shorts
        BDECL(0) BDECL(1) BDECL(2) BDECL(3) BDECL(4) BDECL(5) BDECL(6)

#define STAGEB(kc, Bb) do { \
        gl_lds16(bsrc0 + (kc), (Bb) + bdst0); \
        gl_lds16(bsrc1 + (kc), (Bb) + bdst1); \
        gl_lds16(bsrc2 + (kc), (Bb) + bdst2); \
        gl_lds16(bsrc3 + (kc), (Bb) + bdst3); \
        gl_lds16(bsrc4 + (kc), (Bb) + bdst4); \
        gl_lds16(bsrc5 + (kc), (Bb) + bdst5); \
        gl_lds16(bsrc6 + (kc), (Bb) + bdst6); } while (0)

        // ---- A staging: 128 rows x 8 subs = 1024 subs; 512 thr x 2 slots
        // UNIFORM: slot0 = tid, slot1 = tid + 512 (= +64 rows, same column
        // -> same swizzle phase, dest +64 rows).
        const int r0a = tid >> 3, c0a = tid & 7;
        const float* asrc0 = x + (size_t)(row0 + r0a) * D_DIM + c0a * 8;
        const float* asrc1 = asrc0 + (size_t)64 * D_DIM;
        const int adst0 = r0a * 64 + ((c0a + r0a) & 7) * 8;   // swizzled
        // (c0a + r0a + 64) & 7 == (c0a + r0a) & 7  ->  adst1 = adst0 + 4096
        // depth-2 ping-pong fp32 sets X/Y; chunk parity == set parity
        float4 aX0lo, aX0hi, aX1lo, aX1hi;
        float4 aY0lo, aY0hi, aY1lo, aY1hi;

#define LOADA_X(kc) do { \
        aX0lo = *reinterpret_cast<const float4*>(asrc0 + (kc));     \
        aX0hi = *reinterpret_cast<const float4*>(asrc0 + (kc) + 4); \
        aX1lo = *reinterpret_cast<const float4*>(asrc1 + (kc));     \
        aX1hi = *reinterpret_cast<const float4*>(asrc1 + (kc) + 4); } while (0)
#define LOADA_Y(kc) do { \
        aY0lo = *reinterpret_cast<const float4*>(asrc0 + (kc));     \
        aY0hi = *reinterpret_cast<const float4*>(asrc0 + (kc) + 4); \
        aY1lo = *reinterpret_cast<const float4*>(asrc1 + (kc));     \
        aY1hi = *reinterpret_cast<const float4*>(asrc1 + (kc) + 4); } while (0)
#define WRITEA_X(Ab) do { \
        *reinterpret_cast<uint4*>((Ab) + adst0)        = cvt8u(aX0lo, aX0hi); \
        *reinterpret_cast<uint4*>((Ab) + adst0 + 4096) = cvt8u(aX1lo, aX1hi); \
        } while (0)
#define WRITEA_Y(Ab) do { \
        *reinterpret_cast<uint4*>((Ab) + adst0)        = cvt8u(aY0lo, aY0hi); \
        *reinterpret_cast<uint4*>((Ab) + adst0 + 4096) = cvt8u(aY1lo, aY1hi); \
        } while (0)

#define LOAD_AFR(m) { const int row_ = mh * 64 + (m) * 16 + l15; \
        const int p_ = (quad + h * 4 + row_) & 7; \
        afr##m = *reinterpret_cast<const bf16x8*>(Ab_ + row_ * 64 + p_ * 8); }
#define LOAD_BFR(n) { const int row_ = (nf * NTPW + (n)) * 16 + l15; \
        const int p_ = (quad + h * 4 + row_) & 7; \
        bfr##n = *reinterpret_cast<const bf16x8*>(Bb_ + row_ * 64 + p_ * 8); }

        // ---- prologue: chunk0 -> buf0 (set X); chunk1 A-loads flying (Y).
        LOADA_X(0);
        WRITEA_X(Abuf[0]);              // compiler auto-drains A(0) (one-time)
        STAGEB(0, Bbuf[0]);             // 7 DMAs (older than A(1))
        __builtin_amdgcn_sched_barrier(0);
        LOADA_Y(BK);                    // chunk 1 -> set Y, stays in flight

        #pragma unroll 1
        for (int c = 0; c < NCHUNK; ++c) {
            const int cur = c & 1;
            const unsigned short* Ab_ = Abuf[cur];
            const unsigned short* Bb_ = Bbuf[cur];
            // invariant at top: outstanding = 7 DMA(c) [oldest] + 4 A(c+1).
            // retire own DMAs; A(c+1) keeps flying ACROSS the barrier.
            if (c == NCHUNK - 1) {
                asm volatile("s_waitcnt vmcnt(0)" ::: "memory");
            } else {
                asm volatile("s_waitcnt vmcnt(4)" ::: "memory");
            }
            asm volatile("s_waitcnt lgkmcnt(0)" ::: "memory");
            __builtin_amdgcn_s_barrier();
            __builtin_amdgcn_sched_barrier(0);
            if (c + 1 < NCHUNK) {
                STAGEB((c + 1) * BK, Bbuf[1 - cur]);   // 7 DMAs FIRST
                __builtin_amdgcn_sched_barrier(0);
                // chunk c+1 lives in set (c+1)&1; auto vmcnt wait (cheap,
                // issued a full chunk ago)
                if (cur == 0) WRITEA_Y(Abuf[1]);
                else          WRITEA_X(Abuf[0]);
                if (c + 2 < NCHUNK) {                  // chunk c+2 -> set c&1
                    if (cur == 0) LOADA_X((c + 2) * BK);
                    else          LOADA_Y((c + 2) * BK);
                }
                __builtin_amdgcn_sched_barrier(0);
            }
            #pragma unroll
            for (int h = 0; h < 2; ++h) {
                bf16x8 afr0, afr1, afr2, afr3;
                bf16x8 bfr0, bfr1, bfr2, bfr3, bfr4, bfr5, bfr6;
                LOAD_AFR(0) LOAD_AFR(1) LOAD_AFR(2) LOAD_AFR(3)
                LOAD_BFR(0) LOAD_BFR(1) LOAD_BFR(2) LOAD_BFR(3)
                LOAD_BFR(4) LOAD_BFR(5) LOAD_BFR(6)
                FOR_MN(MFMA_MN)
            }
        }
    } else {
        // fallback: both fp32 direct (no ws), clamped pad cols, plain loop
        const float* af = x + (size_t)(row0 + mh * 64 + l15) * D_DIM + quad * 8;
#define PBF(n) const float* pbf##n; { \
        int r_ = (nf * NTPW + (n)) * 16 + l15; if (r_ > N_COLS - 1) r_ = 0; \
        pbf##n = (const float*)b_any + (size_t)r_ * D_DIM + quad * 8; }
        PBF(0) PBF(1) PBF(2) PBF(3) PBF(4) PBF(5) PBF(6)
        for (int step = 0; step < 32; ++step) {
            const int off = step * 32;
            bf16x8 afr0, afr1, afr2, afr3;
            bf16x8 bfr0, bfr1, bfr2, bfr3, bfr4, bfr5, bfr6;
#define LAF2(m) afr##m = cvt8( \
            *reinterpret_cast<const float4*>(af + (size_t)(m) * 16 * D_DIM + off), \
            *reinterpret_cast<const float4*>(af + (size_t)(m) * 16 * D_DIM + off + 4));
#define LBF2(n) bfr##n = cvt8( \
            *reinterpret_cast<const float4*>(pbf##n + off), \
            *reinterpret_cast<const float4*>(pbf##n + off + 4));
            LAF2(0) LAF2(1) LAF2(2) LAF2(3)
            LBF2(0) LBF2(1) LBF2(2) LBF2(3) LBF2(4) LBF2(5) LBF2(6)
            FOR_MN(MFMA_MN)
        }
    }

    // ---- epilogue ----
    // C/D layout: col = l15 (within tile), row = quad*4 + reg   [m89/m91]
    const float fcw0 = fcw[l15 & 3];        // fc_w[0][k], k = col&3
    const float fcw1 = fcw[4 + (l15 & 3)];  // fc_w[1][k]

    // pad cols (>=400): bias=0, tw=0 -> exact zero contribution
#define PRE_N(n) \
    const int  col##n  = (nf * NTPW + (n)) * 16 + l15; \
    const bool ok##n   = (col##n < N_COLS); \
    const float bias##n = ok##n ? b1[ok##n ? col##n : 0] : 0.0f; \
    const float tw##n   = ok##n ? fw[ok##n ? (col##n >> 2) : 0] : 0.0f;
    PRE_N(0) PRE_N(1) PRE_N(2) PRE_N(3) PRE_N(4) PRE_N(5) PRE_N(6)

    // per (m,r): q = sum over n of fw[t]*sigmoid(split)*S ; then 16-lane sum.
    // k-sum S: lanes ^1,^2 (l15 bits 0-1 are k within tree).
#define EPI_TERM(m,r,n) { \
        const float split_ = acc##m##n[r] + bias##n; \
        float s_ = split_; \
        s_ += __shfl_xor(s_, 1); \
        s_ += __shfl_xor(s_, 2); \
        const float leaf_ = 1.0f / (1.0f + __expf(-split_)); \
        const float val_ = tw##n * leaf_ * s_; \
        q0 += val_ * fcw0; q1 += val_ * fcw1; }

#define EPI_ONE(m,r) { \
        float q0 = 0.f, q1 = 0.f; \
        EPI_TERM(m,r,0) EPI_TERM(m,r,1) EPI_TERM(m,r,2) EPI_TERM(m,r,3) \
        EPI_TERM(m,r,4) EPI_TERM(m,r,5) EPI_TERM(m,r,6) \
        q0 += __shfl_xor(q0, 1); q0 += __shfl_xor(q0, 2); \
        q0 += __shfl_xor(q0, 4); q0 += __shfl_xor(q0, 8); \
        q1 += __shfl_xor(q1, 1); q1 += __shfl_xor(q1, 2); \
        q1 += __shfl_xor(q1, 4); q1 += __shfl_xor(q1, 8); \
        const int row_ = mh * 64 + (m) * 16 + quad * 4 + (r);   /* 0..127 */ \
        if (l15 == 0) Pbuf[(row_ * 4 + nf) * 2 + 0] = q0; \
        if (l15 == 1) Pbuf[(row_ * 4 + nf) * 2 + 1] = q1; }

#define EPI_M(m) EPI_ONE(m,0) EPI_ONE(m,1) EPI_ONE(m,2) EPI_ONE(m,3)
    EPI_M(0) EPI_M(1) EPI_M(2) EPI_M(3)

    __syncthreads();

    if (tid < 2 * BM) {
        const int r = tid >> 1, j = tid & 1;
        float s = fcb[j];
        #pragma unroll
        for (int w = 0; w < 4; ++w)
            s += Pbuf[(r * 4 + w) * 2 + j];
        out[(row0 + r) * 2 + j] = s;
    }
}

extern "C" void kernel_launch(void* const* d_in, const int* in_sizes, int n_in,
                              void* d_out, int out_size, void* d_ws, size_t ws_size,
                              hipStream_t stream) {
    const float* x   = (const float*)d_in[0];
    const float* W1  = (const float*)d_in[1];
    const float* b1  = (const float*)d_in[2];
    const float* fw  = (const float*)d_in[3];
    const float* fcw = (const float*)d_in[4];
    const float* fcb = (const float*)d_in[5];
    float* out = (float*)d_out;

    const size_t pad_elems = (size_t)NPAD * D_DIM;    // 458,752
    if (ws_size >= pad_elems * sizeof(unsigned short)) {
        unsigned short* w1b = (unsigned short*)d_ws;
        cvt_pad_bf16_kernel<<<(int)(pad_elems / 2048), 256, 0, stream>>>(W1, w1b);
        xgb_v14<0><<<B_ROWS / BM, THREADS, 0, stream>>>(
            x, (const void*)w1b, b1, fw, fcw, fcb, out);
    } else {
        xgb_v14<2><<<B_ROWS / BM, THREADS, 0, stream>>>(
            x, (const void*)W1, b1, fw, fcw, fcb, out);
    }
}